// Round 1
// baseline (401.918 us; speedup 1.0000x reference)
//
#include <hip/hip_runtime.h>
#include <hip/hip_bf16.h>

// Problem constants (from reference): BATCH=131072, FEAT=512, NUM_CLASS=8192.
// Strategy: bucket rows by class (hist -> scan -> scatter), then one block per
// class gathers & sums its rows with float4 loads. No float atomics.

#define FEAT 512
#define FEAT4 128           // FEAT / 4 floats per float4
#define SCAN_THREADS 256

__global__ void k_zero(int* __restrict__ counts, int n) {
    int i = blockIdx.x * blockDim.x + threadIdx.x;
    if (i < n) counts[i] = 0;
}

__global__ void k_hist(const int* __restrict__ targets, int* __restrict__ counts, int batch) {
    int i = blockIdx.x * blockDim.x + threadIdx.x;
    if (i < batch) atomicAdd(&counts[targets[i]], 1);
}

// Exclusive scan of NUM_CLASS bins with a single block of 256 threads.
// bins_per_thread must equal num_class / 256 (== 32 here).
__global__ void k_scan(const int* __restrict__ counts, int* __restrict__ offsets,
                       int* __restrict__ fill, int num_class) {
    __shared__ int sums[SCAN_THREADS];
    const int t = threadIdx.x;
    const int bins = num_class / SCAN_THREADS;   // 32
    int local[32];
    int base = t * bins;
    int s = 0;
    #pragma unroll
    for (int i = 0; i < 32; ++i) { local[i] = counts[base + i]; s += local[i]; }
    sums[t] = s;
    __syncthreads();
    // Hillis-Steele inclusive scan over 256 partials
    for (int off = 1; off < SCAN_THREADS; off <<= 1) {
        int v = (t >= off) ? sums[t - off] : 0;
        __syncthreads();
        sums[t] += v;
        __syncthreads();
    }
    int run = sums[t] - s;   // exclusive prefix for this thread's range
    #pragma unroll
    for (int i = 0; i < 32; ++i) {
        offsets[base + i] = run;
        fill[base + i]    = run;
        run += local[i];
    }
}

__global__ void k_scatter(const int* __restrict__ targets, int* __restrict__ fill,
                          int* __restrict__ rows, int batch) {
    int i = blockIdx.x * blockDim.x + threadIdx.x;
    if (i < batch) {
        int pos = atomicAdd(&fill[targets[i]], 1);
        rows[pos] = i;
    }
}

// One block (128 threads) per class: acc = class_sums[c] + sum of its rows.
// Each thread owns one float4 column slice (128*4 = 512 feats).
__global__ __launch_bounds__(128) void k_sum(const float4* __restrict__ batch,
                                             const float4* __restrict__ csums,
                                             const int* __restrict__ offsets,
                                             const int* __restrict__ counts,
                                             const int* __restrict__ rows,
                                             float4* __restrict__ out) {
    const int c = blockIdx.x;
    const int t = threadIdx.x;      // 0..127
    const int start = offsets[c];
    const int n     = counts[c];

    float4 acc = csums[(size_t)c * FEAT4 + t];

    __shared__ int sidx[512];
    for (int chunk = 0; chunk < n; chunk += 512) {
        const int m = min(n - chunk, 512);
        for (int j = t; j < m; j += 128) sidx[j] = rows[start + chunk + j];
        __syncthreads();
        for (int j = 0; j < m; ++j) {
            float4 v = batch[(size_t)sidx[j] * FEAT4 + t];
            acc.x += v.x; acc.y += v.y; acc.z += v.z; acc.w += v.w;
        }
        __syncthreads();
    }
    out[(size_t)c * FEAT4 + t] = acc;
}

// ---------- fallback: plain atomic scatter-add (if ws too small) ----------
__global__ void k_copy(const float4* __restrict__ src, float4* __restrict__ dst, int n4) {
    int i = blockIdx.x * blockDim.x + threadIdx.x;
    if (i < n4) dst[i] = src[i];
}

__global__ __launch_bounds__(128) void k_atomic(const float4* __restrict__ batch,
                                                const int* __restrict__ targets,
                                                float* __restrict__ out, int batch_n) {
    const int r = blockIdx.x;       // one block per row
    const int t = threadIdx.x;      // 0..127
    if (r >= batch_n) return;
    float4 v = batch[(size_t)r * FEAT4 + t];
    float* o = out + (size_t)targets[r] * FEAT + t * 4;
    atomicAdd(o + 0, v.x);
    atomicAdd(o + 1, v.y);
    atomicAdd(o + 2, v.z);
    atomicAdd(o + 3, v.w);
}

extern "C" void kernel_launch(void* const* d_in, const int* in_sizes, int n_in,
                              void* d_out, int out_size, void* d_ws, size_t ws_size,
                              hipStream_t stream) {
    const float* batch_samples = (const float*)d_in[0];
    const float* class_sums    = (const float*)d_in[1];
    const int*   targets       = (const int*)d_in[2];
    // d_in[3] (idx) is unused by the forward math.

    const int batch     = in_sizes[2];          // 131072
    const int num_class = out_size / FEAT;      // 8192
    float* out = (float*)d_out;

    // Workspace layout
    const size_t need = (size_t)num_class * 4 * 3 + (size_t)batch * 4;
    if (ws_size >= need) {
        int* counts  = (int*)d_ws;
        int* offsets = counts + num_class;
        int* fill    = offsets + num_class;
        int* rows    = fill + num_class;

        k_zero<<<(num_class + 255) / 256, 256, 0, stream>>>(counts, num_class);
        k_hist<<<(batch + 255) / 256, 256, 0, stream>>>(targets, counts, batch);
        k_scan<<<1, SCAN_THREADS, 0, stream>>>(counts, offsets, fill, num_class);
        k_scatter<<<(batch + 255) / 256, 256, 0, stream>>>(targets, fill, rows, batch);
        k_sum<<<num_class, 128, 0, stream>>>((const float4*)batch_samples,
                                             (const float4*)class_sums,
                                             offsets, counts, rows,
                                             (float4*)out);
    } else {
        // Fallback: copy class_sums into out, then atomic scatter-add.
        const int n4 = out_size / 4;
        k_copy<<<(n4 + 255) / 256, 256, 0, stream>>>((const float4*)class_sums,
                                                     (float4*)out, n4);
        k_atomic<<<batch, 128, 0, stream>>>((const float4*)batch_samples,
                                            targets, out, batch);
    }
}